// Round 15
// baseline (220.945 us; speedup 1.0000x reference)
//
#include <hip/hip_runtime.h>

// ---------------- problem constants ----------------
#define BATCH 512
#define SDIM  680          // i dimension (680)
#define DIP   768          // i padded to 768 = 24*32
#define ABC   55296        // 48*24*48
#define NB_   24
#define SQRT2F 1.4142135623730951f

typedef __attribute__((ext_vector_type(8))) short bf16x8;
typedef __attribute__((ext_vector_type(4))) float f32x4;

// ws layout (bytes)
#define DP_BYTES   ((size_t)ABC * DIP * 2)            // 84,934,656
#define DPT_BYTES  ((size_t)DIP * ABC * 2)            // 84,934,656
#define FP_BYTES   ((size_t)BATCH * DIP * 2)
#define G_BYTES    ((size_t)BATCH * ABC * 2)
#define DP_OFF     ((size_t)0)
#define DPT_OFF    (DP_OFF + DP_BYTES)
#define FP_OFF     (DPT_OFF + DPT_BYTES)
#define G_OFF      (FP_OFF + FP_BYTES)
#define WS_NEEDED  (G_OFF + G_BYTES)                  // 227,278,848

// gemm2 split-K: 55296 = 32 * 1728, 1728 = 27 K-tiles of 64
#define SPLITK 32
#define KC     1728
// P (bf16 partials, 25.2 MB) overlays Dp — Dp dead after gemm1; stream order serializes.
#define P_OFF  DP_OFF

__device__ __forceinline__ unsigned short f2bf(float f) {
  unsigned int u = __float_as_uint(f);
  unsigned int r = (u + 0x7FFFu + ((u >> 16) & 1u)) >> 16;   // RNE
  return (unsigned short)r;
}

__device__ __forceinline__ float bf2f(unsigned int bits16) {
  return __uint_as_float(bits16 << 16);
}

__device__ __forceinline__ void stage16(const void* g, const void* l) {
  __builtin_amdgcn_global_load_lds(
      (const __attribute__((address_space(1))) unsigned int*)g,
      (__attribute__((address_space(3))) unsigned int*)l, 16, 0, 0);
}

// ---------------- conv_dp: D (f32) -> Dp (bf16 [ABC][768]) ----------------
// r5-verified pure streaming: fully sequential reads AND writes.
__global__ __launch_bounds__(256) void conv_dp(const float* __restrict__ D,
                                               unsigned short* __restrict__ Dp) {
  const int tid = blockIdx.x * 256 + threadIdx.x;   // 663,552 threads
  #pragma unroll
  for (int k = 0; k < 8; ++k) {
    const int u = tid + k * 663552;                 // 5,308,416 units
    const int r = u / 96, c = u % 96;               // 768/8 = 96 units per row
    uint4 p = make_uint4(0u, 0u, 0u, 0u);
    if (c < 85) {                                   // 680/8 = 85 valid units
      const float4 a = *(const float4*)(D + (size_t)r * SDIM + c * 8);
      const float4 b = *(const float4*)(D + (size_t)r * SDIM + c * 8 + 4);
      p.x = f2bf(a.x) | ((unsigned int)f2bf(a.y) << 16);
      p.y = f2bf(a.z) | ((unsigned int)f2bf(a.w) << 16);
      p.z = f2bf(b.x) | ((unsigned int)f2bf(b.y) << 16);
      p.w = f2bf(b.z) | ((unsigned int)f2bf(b.w) << 16);
    }
    *(uint4*)(Dp + (size_t)r * DIP + c * 8) = p;
  }
}

// ---------------- conv_dpt: D (f32) -> DpT (bf16 [768][ABC]) ----------------
// r14-measured ~28us when run AFTER gemm1 (D L3-warm). Vectorized LDS transpose.
#define CBP 264
__global__ __launch_bounds__(256, 4) void conv_dpt(const float* __restrict__ D,
                                                   unsigned short* __restrict__ DpT) {
  __shared__ unsigned short T[64 * CBP];    // 33,792 B
  const int bid = blockIdx.x;               // 2592 = 8 XCD * 324
  const int logical = (bid & 7) * 324 + (bid >> 3);
  const int bx = logical / 12;              // abc tile (256 wide), 0..215
  const int by = logical % 12;              // i tile (64 wide), 0..11
  const int t = threadIdx.x;

  #pragma unroll
  for (int k = 0; k < 4; ++k) {
    const int micro = t + k * 256;          // 0..1023 micro-tiles (4x4)
    const int r4 = micro >> 4;              // 0..63
    const int c4 = micro & 15;              // 0..15
    const int gr = bx * 256 + r4 * 4;
    const int gi = by * 64 + c4 * 4;
    float4 v[4];
    const bool valid = gi < SDIM;
    #pragma unroll
    for (int dr = 0; dr < 4; ++dr)
      v[dr] = valid ? *(const float4*)(D + (size_t)(gr + dr) * SDIM + gi)
                    : make_float4(0.f, 0.f, 0.f, 0.f);
    const float* fv = reinterpret_cast<const float*>(v);
    #pragma unroll
    for (int j = 0; j < 4; ++j) {
      ushort4 p;
      p.x = f2bf(fv[0 * 4 + j]); p.y = f2bf(fv[1 * 4 + j]);
      p.z = f2bf(fv[2 * 4 + j]); p.w = f2bf(fv[3 * 4 + j]);
      *(ushort4*)&T[(c4 * 4 + j) * CBP + r4 * 4] = p;
    }
  }
  __syncthreads();
  #pragma unroll
  for (int k = 0; k < 8; ++k) {
    const int v2 = t + k * 256;
    const int c = v2 >> 5;
    const int u = v2 & 31;
    const uint4 q = *(const uint4*)&T[c * CBP + u * 8];
    *(uint4*)(DpT + (size_t)(by * 64 + c) * ABC + bx * 256 + u * 8) = q;
  }
}

// ---------------- convert F -> Fp [BATCH][768] bf16 ----------------
__global__ __launch_bounds__(256) void convert_f(const float* __restrict__ F,
                                                 unsigned short* __restrict__ Fp) {
  const int u = blockIdx.x * 256 + threadIdx.x;
  if (u >= BATCH * (DIP / 8)) return;
  const int n = u / (DIP / 8), s = u % (DIP / 8);
  const int i = s * 8;
  float4 a = make_float4(0.f, 0.f, 0.f, 0.f), b = a;
  if (i < SDIM) {
    a = *(const float4*)(F + (size_t)n * SDIM + i);
    b = *(const float4*)(F + (size_t)n * SDIM + i + 4);
  }
  uint4 p;
  p.x = f2bf(a.x) | ((unsigned int)f2bf(a.y) << 16);
  p.y = f2bf(a.z) | ((unsigned int)f2bf(a.w) << 16);
  p.z = f2bf(b.x) | ((unsigned int)f2bf(b.y) << 16);
  p.w = f2bf(b.z) | ((unsigned int)f2bf(b.w) << 16);
  *(uint4*)(Fp + (size_t)n * DIP + i) = p;
}

// ---------------- GEMM1: G[n][abc] = relu(F·D^T)·sqrt2·qw[b]  (r12 core, ~47us measured) ----------------
__global__ __launch_bounds__(512, 1) void gemm1(const unsigned short* __restrict__ Fp,
                                                const unsigned short* __restrict__ Dp,
                                                const float* __restrict__ qw,
                                                unsigned short* __restrict__ G) {
  __shared__ short LDS_[65536];          // 128 KiB: A[2][16384], B[2][16384]
  __shared__ float qws[NB_];
  short* Ab0 = LDS_;
  short* Bb0 = LDS_ + 32768;
  const int t = threadIdx.x;
  const int bid = blockIdx.x;            // 432 = 8 XCD * 54
  const int logical = (bid & 7) * 54 + (bid >> 3);
  const int nt = logical >> 1, mt = logical & 1;
  const int m0 = mt * 256, n0 = nt * 256;
  if (t < NB_) qws[t] = qw[t] * SQRT2F;

  const int row0 = t >> 3;
  const int scol = ((t & 7) ^ (row0 & 7)) * 8;
  const unsigned short* Asrc = Fp + (size_t)(m0 + row0) * DIP + scol;
  const unsigned short* Bsrc = Dp + (size_t)(n0 + row0) * DIP + scol;

  const int lane = t & 63, wid = t >> 6;
  const int wm = wid >> 2, wn = wid & 3;
  const int fr = lane & 15, fk = lane >> 4;
  const int slotL0 = ((fk) ^ (fr & 7)) * 8;
  const int slotL1 = ((4 + fk) ^ (fr & 7)) * 8;

  f32x4 acc[8][4];
  #pragma unroll
  for (int i = 0; i < 8; ++i)
    #pragma unroll
    for (int j = 0; j < 4; ++j)
      #pragma unroll
      for (int k = 0; k < 4; ++k) acc[i][j][k] = 0.f;

  auto stage = [&](int b, int kt) {
    const unsigned short* ga = Asrc + kt * 64;
    const unsigned short* gb = Bsrc + kt * 64;
    short* la = Ab0 + b * 16384;
    short* lb = Bb0 + b * 16384;
    #pragma unroll
    for (int j = 0; j < 4; ++j) {
      stage16(ga + (size_t)j * 64 * DIP, la + (j * 512 + t) * 8);
      stage16(gb + (size_t)j * 64 * DIP, lb + (j * 512 + t) * 8);
    }
  };

  stage(0, 0);
  const int KT = DIP / 64;   // 12
  for (int kt = 0; kt < KT; ++kt) {
    asm volatile("s_waitcnt vmcnt(0)" ::: "memory");
    __builtin_amdgcn_s_barrier();
    if (kt + 1 < KT) stage((kt + 1) & 1, kt + 1);
    const short* At = Ab0 + (kt & 1) * 16384;
    const short* Bt = Bb0 + (kt & 1) * 16384;
    #pragma unroll
    for (int ks = 0; ks < 2; ++ks) {
      const int slot = ks ? slotL1 : slotL0;
      bf16x8 bv[4], av[8];
      #pragma unroll
      for (int ni = 0; ni < 4; ++ni)
        bv[ni] = *(const bf16x8*)&Bt[(wn * 64 + ni * 16 + fr) * 64 + slot];
      #pragma unroll
      for (int mi = 0; mi < 8; ++mi)
        av[mi] = *(const bf16x8*)&At[(wm * 128 + mi * 16 + fr) * 64 + slot];
      __builtin_amdgcn_s_setprio(1);
      #pragma unroll
      for (int mi = 0; mi < 8; ++mi)
        #pragma unroll
        for (int ni = 0; ni < 4; ++ni)
          acc[mi][ni] = __builtin_amdgcn_mfma_f32_16x16x32_bf16(av[mi], bv[ni], acc[mi][ni], 0, 0, 0);
      __builtin_amdgcn_s_setprio(0);
    }
  }

  __syncthreads();
  #pragma unroll
  for (int mi = 0; mi < 8; ++mi) {
    const int row = wm * 128 + mi * 16 + fk * 4;
    #pragma unroll
    for (int ni = 0; ni < 4; ++ni) {
      const int colL = wn * 64 + ni * 16 + fr;
      const float qv = qws[((n0 + colL) / 48) % NB_];
      #pragma unroll
      for (int r = 0; r < 4; ++r)
        LDS_[(row + r) * 256 + colL] = (short)f2bf(fmaxf(acc[mi][ni][r], 0.f) * qv);
    }
  }
  __syncthreads();
  {
    const int row = t >> 1, h = t & 1;
    const unsigned short* src = (const unsigned short*)&LDS_[row * 256 + h * 128];
    unsigned short* dst = G + (size_t)(m0 + row) * ABC + n0 + h * 128;
    #pragma unroll
    for (int c = 0; c < 16; ++c)
      *(uint4*)(dst + c * 8) = *(const uint4*)(src + c * 8);
  }
}

// ---------------- GEMM2: P[sk][n][i] (bf16) = sum_{k in chunk} G[n][k]*DpT[i][k] ----------------
// Verified core: 256x192 tiles, grid 256 = one packed round.
__global__ __launch_bounds__(512, 1) void gemm2(const unsigned short* __restrict__ Gm,
                                                const unsigned short* __restrict__ DpT,
                                                unsigned short* __restrict__ P) {
  __shared__ short LDS_[57344];          // A[2][16384] + B[2][12288]
  short* Ab0 = LDS_;
  short* Bb0 = LDS_ + 32768;
  const int t = threadIdx.x;
  const int bid = blockIdx.x;            // 256 = 8 XCD * 32
  const int logical = (bid & 7) * 32 + (bid >> 3);
  const int sk = logical >> 3;
  const int rem = logical & 7;
  const int mt = rem >> 2, nt2 = rem & 3;
  const int m0 = mt * 256, n0 = nt2 * 192;
  const size_t kbase = (size_t)sk * KC;

  const int row0 = t >> 3;
  const int scol = ((t & 7) ^ (row0 & 7)) * 8;
  const unsigned short* Asrc = Gm  + (size_t)(m0 + row0) * ABC + kbase + scol;
  const unsigned short* Bsrc = DpT + (size_t)(n0 + row0) * ABC + kbase + scol;

  const int lane = t & 63, wid = t >> 6;
  const int wm = wid >> 2, wn = wid & 3;   // wave tile 128M x 48N
  const int fr = lane & 15, fk = lane >> 4;
  const int slotL0 = ((fk) ^ (fr & 7)) * 8;
  const int slotL1 = ((4 + fk) ^ (fr & 7)) * 8;

  f32x4 acc[8][3];
  #pragma unroll
  for (int i = 0; i < 8; ++i)
    #pragma unroll
    for (int j = 0; j < 3; ++j)
      #pragma unroll
      for (int k = 0; k < 4; ++k) acc[i][j][k] = 0.f;

  auto stage = [&](int b, int kt) {
    const unsigned short* ga = Asrc + kt * 64;
    const unsigned short* gb = Bsrc + kt * 64;
    short* la = Ab0 + b * 16384;
    short* lb = Bb0 + b * 12288;
    #pragma unroll
    for (int j = 0; j < 4; ++j)
      stage16(ga + (size_t)j * 64 * ABC, la + (j * 512 + t) * 8);
    #pragma unroll
    for (int j = 0; j < 3; ++j)
      stage16(gb + (size_t)j * 64 * ABC, lb + (j * 512 + t) * 8);
  };

  stage(0, 0);
  const int KT = KC / 64;   // 27
  for (int kt = 0; kt < KT; ++kt) {
    asm volatile("s_waitcnt vmcnt(0)" ::: "memory");
    __builtin_amdgcn_s_barrier();
    if (kt + 1 < KT) stage((kt + 1) & 1, kt + 1);
    const short* At = Ab0 + (kt & 1) * 16384;
    const short* Bt = Bb0 + (kt & 1) * 12288;
    #pragma unroll
    for (int ks = 0; ks < 2; ++ks) {
      const int slot = ks ? slotL1 : slotL0;
      bf16x8 bv[3], av[8];
      #pragma unroll
      for (int ni = 0; ni < 3; ++ni)
        bv[ni] = *(const bf16x8*)&Bt[(wn * 48 + ni * 16 + fr) * 64 + slot];
      #pragma unroll
      for (int mi = 0; mi < 8; ++mi)
        av[mi] = *(const bf16x8*)&At[(wm * 128 + mi * 16 + fr) * 64 + slot];
      __builtin_amdgcn_s_setprio(1);
      #pragma unroll
      for (int mi = 0; mi < 8; ++mi)
        #pragma unroll
        for (int ni = 0; ni < 3; ++ni)
          acc[mi][ni] = __builtin_amdgcn_mfma_f32_16x16x32_bf16(av[mi], bv[ni], acc[mi][ni], 0, 0, 0);
      __builtin_amdgcn_s_setprio(0);
    }
  }

  __syncthreads();
  #pragma unroll
  for (int mi = 0; mi < 8; ++mi) {
    const int row = wm * 128 + mi * 16 + fk * 4;
    #pragma unroll
    for (int ni = 0; ni < 3; ++ni) {
      const int colL = wn * 48 + ni * 16 + fr;
      #pragma unroll
      for (int r = 0; r < 4; ++r)
        LDS_[(row + r) * 192 + colL] = (short)f2bf(acc[mi][ni][r]);
    }
  }
  __syncthreads();
  {
    const int row = t >> 1, h = t & 1;
    const unsigned short* src = (const unsigned short*)&LDS_[row * 192 + h * 96];
    unsigned short* dst = P + (size_t)sk * BATCH * DIP +
                          (size_t)(m0 + row) * DIP + n0 + h * 96;
    #pragma unroll
    for (int c = 0; c < 12; ++c)
      *(uint4*)(dst + c * 8) = *(const uint4*)(src + c * 8);
  }
}

// ---------------- reduce: out[n][i] = sum_s P[s][n][i]  (bf16 partials) ----------------
__global__ __launch_bounds__(256) void reduce_p(const unsigned short* __restrict__ P,
                                                float* __restrict__ out) {
  const int u = blockIdx.x * 256 + threadIdx.x;
  const int n = u / (SDIM / 4), q = u % (SDIM / 4);
  const int i = q * 4;
  const unsigned short* base = P + (size_t)n * DIP + i;
  const size_t stride = (size_t)BATCH * DIP;
  float s0 = 0.f, s1 = 0.f, s2 = 0.f, s3 = 0.f;
  #pragma unroll 4
  for (int s = 0; s < SPLITK; ++s) {
    const uint2 v = *(const uint2*)(base + (size_t)s * stride);
    s0 += bf2f(v.x & 0xffffu);
    s1 += __uint_as_float(v.x & 0xffff0000u);
    s2 += bf2f(v.y & 0xffffu);
    s3 += __uint_as_float(v.y & 0xffff0000u);
  }
  float4 r; r.x = s0; r.y = s1; r.z = s2; r.w = s3;
  *(float4*)(out + (size_t)n * SDIM + i) = r;
}

// ---------------- fallback (no workspace): slow but correct ----------------
__global__ __launch_bounds__(256) void so3_fallback(const float* __restrict__ F,
                                                    const float* __restrict__ D,
                                                    const float* __restrict__ qw,
                                                    float* __restrict__ out) {
  const int n = blockIdx.x;
  __shared__ float fsh[SDIM];
  __shared__ float acc[SDIM];
  __shared__ float gch[256];
  for (int i = threadIdx.x; i < SDIM; i += 256) {
    fsh[i] = F[(size_t)n * SDIM + i];
    acc[i] = 0.f;
  }
  __syncthreads();
  for (int c0 = 0; c0 < ABC; c0 += 256) {
    const int r = c0 + threadIdx.x;
    const float* dr = D + (size_t)r * SDIM;
    float s = 0.f;
    for (int i = 0; i < SDIM; ++i) s += fsh[i] * dr[i];
    s = fmaxf(s, 0.f) * SQRT2F * qw[(r / 48) % NB_];
    gch[threadIdx.x] = s;
    __syncthreads();
    for (int i = threadIdx.x; i < SDIM; i += 256) {
      float a = 0.f;
      for (int tt = 0; tt < 256; ++tt) a += gch[tt] * D[(size_t)(c0 + tt) * SDIM + i];
      acc[i] += a;
    }
    __syncthreads();
  }
  for (int i = threadIdx.x; i < SDIM; i += 256) out[(size_t)n * SDIM + i] = acc[i];
}

// ---------------- launch ----------------
extern "C" void kernel_launch(void* const* d_in, const int* in_sizes, int n_in,
                              void* d_out, int out_size, void* d_ws, size_t ws_size,
                              hipStream_t stream) {
  const float* F  = (const float*)d_in[0];
  const float* D  = (const float*)d_in[1];
  const float* qw = (const float*)d_in[2];
  float* out = (float*)d_out;

  if (ws_size < WS_NEEDED) {
    so3_fallback<<<BATCH, 256, 0, stream>>>(F, D, qw, out);
    return;
  }

  unsigned short* Dp  = (unsigned short*)((char*)d_ws + DP_OFF);
  unsigned short* DpT = (unsigned short*)((char*)d_ws + DPT_OFF);
  unsigned short* Fp  = (unsigned short*)((char*)d_ws + FP_OFF);
  unsigned short* G   = (unsigned short*)((char*)d_ws + G_OFF);
  unsigned short* P   = (unsigned short*)((char*)d_ws + P_OFF);   // overlays Dp (dead after gemm1)

  conv_dp<<<2592, 256, 0, stream>>>(D, Dp);          // streaming, warms L3 with D
  convert_f<<<192, 256, 0, stream>>>(F, Fp);
  gemm1<<<432, 512, 0, stream>>>(Fp, Dp, qw, G);
  conv_dpt<<<2592, 256, 0, stream>>>(D, DpT);        // D L3-warm
  gemm2<<<256, 512, 0, stream>>>(G, DpT, P);
  reduce_p<<<340, 256, 0, stream>>>(P, out);
}

// Round 16
// 185.137 us; speedup vs baseline: 1.1934x; 1.1934x over previous
//
#include <hip/hip_runtime.h>

// ---------------- problem constants ----------------
#define BATCH 512
#define SDIM  680          // i dimension (680)
#define DIP   768          // i padded to 768 = 24*32
#define ABC   55296        // 48*24*48
#define NB_   24
#define SQRT2F 1.4142135623730951f

typedef __attribute__((ext_vector_type(8))) short bf16x8;
typedef __attribute__((ext_vector_type(4))) float f32x4;

// ws layout (bytes)
#define DP_BYTES   ((size_t)ABC * DIP * 2)            // 84,934,656
#define DPT_BYTES  ((size_t)DIP * ABC * 2)            // 84,934,656
#define FP_BYTES   ((size_t)BATCH * DIP * 2)
#define G_BYTES    ((size_t)BATCH * ABC * 2)
#define DP_OFF     ((size_t)0)
#define DPT_OFF    (DP_OFF + DP_BYTES)
#define FP_OFF     (DPT_OFF + DPT_BYTES)
#define G_OFF      (FP_OFF + FP_BYTES)
#define WS_NEEDED  (G_OFF + G_BYTES)                  // 227,278,848

// gemm2 split-K: 55296 = 32 * 1728, 1728 = 27 K-tiles of 64
#define SPLITK 32
#define KC     1728
// P (bf16 partials, 25.2 MB) overlays Dp — Dp dead after gemm1.
#define P_OFF  DP_OFF

__device__ __forceinline__ unsigned short f2bf(float f) {
  unsigned int u = __float_as_uint(f);
  unsigned int r = (u + 0x7FFFu + ((u >> 16) & 1u)) >> 16;   // RNE
  return (unsigned short)r;
}

__device__ __forceinline__ float bf2f(unsigned int bits16) {
  return __uint_as_float(bits16 << 16);
}

__device__ __forceinline__ void stage16(const void* g, const void* l) {
  __builtin_amdgcn_global_load_lds(
      (const __attribute__((address_space(1))) unsigned int*)g,
      (__attribute__((address_space(3))) unsigned int*)l, 16, 0, 0);
}

// ---------------- conv_both v3: D (f32) -> Dp (bf16 [ABC][768]) AND DpT (bf16 [768][ABC]) ----------------
// One D read (320 MB total traffic). v3 fixes r12's two limiters:
//  (1) ALL 16 float4 loads issued before any use (r12: VGPR=52 => serialized waits);
//  (2) group-XOR swizzle h = g ^ ((c>>2)&7) on the LDS transpose tile:
//      phase-A writes 8-way -> 2-way (free); phase-B reads unit w = u^(sc>>1),
//      halves swapped iff sc&1 (verified: g(2w) = 2u ^ (sc&1)).
#define CBP 264
__global__ __launch_bounds__(256, 4) void conv_both(const float* __restrict__ D,
                                                    unsigned short* __restrict__ Dp,
                                                    unsigned short* __restrict__ DpT) {
  __shared__ unsigned short T[64 * CBP];    // 33,792 B
  const int bid = blockIdx.x;               // 2592 = 8 XCD * 324
  const int logical = (bid & 7) * 324 + (bid >> 3);
  const int bx = logical / 12;              // abc tile (256 wide), 0..215
  const int by = logical % 12;              // i tile (64 wide), 0..11
  const int t = threadIdx.x;

  // phase A0: issue ALL loads (16 float4 in registers)
  float4 v[4][4];
  #pragma unroll
  for (int k = 0; k < 4; ++k) {
    const int micro = t + k * 256;          // (r4, c4) micro-tile
    const int r4 = micro >> 4;              // 0..63
    const int c4 = micro & 15;              // 0..15
    const int gr = bx * 256 + r4 * 4;
    const int gi = by * 64 + c4 * 4;
    const bool valid = gi < SDIM;           // 680 % 4 == 0: all-or-nothing
    #pragma unroll
    for (int dr = 0; dr < 4; ++dr)
      v[k][dr] = valid ? *(const float4*)(D + (size_t)(gr + dr) * SDIM + gi)
                       : make_float4(0.f, 0.f, 0.f, 0.f);
  }

  // phase A1: convert; Dp direct rows (128B runs); swizzled LDS transpose writes
  #pragma unroll
  for (int k = 0; k < 4; ++k) {
    const int micro = t + k * 256;
    const int r4 = micro >> 4;
    const int c4 = micro & 15;
    const int gr = bx * 256 + r4 * 4;
    const int gi = by * 64 + c4 * 4;
    const float* fv = reinterpret_cast<const float*>(&v[k][0]);
    #pragma unroll
    for (int dr = 0; dr < 4; ++dr) {
      ushort4 p;
      p.x = f2bf(fv[dr * 4 + 0]); p.y = f2bf(fv[dr * 4 + 1]);
      p.z = f2bf(fv[dr * 4 + 2]); p.w = f2bf(fv[dr * 4 + 3]);
      *(ushort4*)(Dp + (size_t)(gr + dr) * DIP + gi) = p;
    }
    const int sc = c4 & 7;                  // == ((c>>2)&7) for c = c4*4+j, j<4
    const int h4 = (r4 ^ sc) * 4;           // swizzled 4-short group start
    #pragma unroll
    for (int j = 0; j < 4; ++j) {
      const int c = c4 * 4 + j;
      ushort4 p;
      p.x = f2bf(fv[0 * 4 + j]); p.y = f2bf(fv[1 * 4 + j]);
      p.z = f2bf(fv[2 * 4 + j]); p.w = f2bf(fv[3 * 4 + j]);
      *(ushort4*)&T[c * CBP + h4] = p;
    }
  }
  __syncthreads();

  // phase B: swizzle-aware reads -> coalesced 512B DpT row runs
  #pragma unroll
  for (int k = 0; k < 8; ++k) {
    const int v2 = t + k * 256;             // 0..2047
    const int c = v2 >> 5;                  // i row 0..63
    const int u = v2 & 31;                  // logical 16B unit along abc
    const int sc = (c >> 2) & 7;
    const int w = u ^ (sc >> 1);            // physical 16B unit
    const uint4 q = *(const uint4*)&T[c * CBP + w * 8];
    uint4 o;
    if (sc & 1) { o.x = q.z; o.y = q.w; o.z = q.x; o.w = q.y; }   // halves swapped
    else        { o = q; }
    *(uint4*)(DpT + (size_t)(by * 64 + c) * ABC + bx * 256 + u * 8) = o;
  }
}

// ---------------- convert F -> Fp [BATCH][768] bf16 ----------------
__global__ __launch_bounds__(256) void convert_f(const float* __restrict__ F,
                                                 unsigned short* __restrict__ Fp) {
  const int u = blockIdx.x * 256 + threadIdx.x;
  if (u >= BATCH * (DIP / 8)) return;
  const int n = u / (DIP / 8), s = u % (DIP / 8);
  const int i = s * 8;
  float4 a = make_float4(0.f, 0.f, 0.f, 0.f), b = a;
  if (i < SDIM) {
    a = *(const float4*)(F + (size_t)n * SDIM + i);
    b = *(const float4*)(F + (size_t)n * SDIM + i + 4);
  }
  uint4 p;
  p.x = f2bf(a.x) | ((unsigned int)f2bf(a.y) << 16);
  p.y = f2bf(a.z) | ((unsigned int)f2bf(a.w) << 16);
  p.z = f2bf(b.x) | ((unsigned int)f2bf(b.y) << 16);
  p.w = f2bf(b.z) | ((unsigned int)f2bf(b.w) << 16);
  *(uint4*)(Fp + (size_t)n * DIP + i) = p;
}

// ---------------- GEMM1: G[n][abc] = relu(F·D^T)·sqrt2·qw[b]  (r12 core, verified) ----------------
__global__ __launch_bounds__(512, 1) void gemm1(const unsigned short* __restrict__ Fp,
                                                const unsigned short* __restrict__ Dp,
                                                const float* __restrict__ qw,
                                                unsigned short* __restrict__ G) {
  __shared__ short LDS_[65536];          // 128 KiB: A[2][16384], B[2][16384]
  __shared__ float qws[NB_];
  short* Ab0 = LDS_;
  short* Bb0 = LDS_ + 32768;
  const int t = threadIdx.x;
  const int bid = blockIdx.x;            // 432 = 8 XCD * 54
  const int logical = (bid & 7) * 54 + (bid >> 3);
  const int nt = logical >> 1, mt = logical & 1;
  const int m0 = mt * 256, n0 = nt * 256;
  if (t < NB_) qws[t] = qw[t] * SQRT2F;

  const int row0 = t >> 3;
  const int scol = ((t & 7) ^ (row0 & 7)) * 8;
  const unsigned short* Asrc = Fp + (size_t)(m0 + row0) * DIP + scol;
  const unsigned short* Bsrc = Dp + (size_t)(n0 + row0) * DIP + scol;

  const int lane = t & 63, wid = t >> 6;
  const int wm = wid >> 2, wn = wid & 3;
  const int fr = lane & 15, fk = lane >> 4;
  const int slotL0 = ((fk) ^ (fr & 7)) * 8;
  const int slotL1 = ((4 + fk) ^ (fr & 7)) * 8;

  f32x4 acc[8][4];
  #pragma unroll
  for (int i = 0; i < 8; ++i)
    #pragma unroll
    for (int j = 0; j < 4; ++j)
      #pragma unroll
      for (int k = 0; k < 4; ++k) acc[i][j][k] = 0.f;

  auto stage = [&](int b, int kt) {
    const unsigned short* ga = Asrc + kt * 64;
    const unsigned short* gb = Bsrc + kt * 64;
    short* la = Ab0 + b * 16384;
    short* lb = Bb0 + b * 16384;
    #pragma unroll
    for (int j = 0; j < 4; ++j) {
      stage16(ga + (size_t)j * 64 * DIP, la + (j * 512 + t) * 8);
      stage16(gb + (size_t)j * 64 * DIP, lb + (j * 512 + t) * 8);
    }
  };

  stage(0, 0);
  const int KT = DIP / 64;   // 12
  for (int kt = 0; kt < KT; ++kt) {
    asm volatile("s_waitcnt vmcnt(0)" ::: "memory");
    __builtin_amdgcn_s_barrier();
    if (kt + 1 < KT) stage((kt + 1) & 1, kt + 1);
    const short* At = Ab0 + (kt & 1) * 16384;
    const short* Bt = Bb0 + (kt & 1) * 16384;
    #pragma unroll
    for (int ks = 0; ks < 2; ++ks) {
      const int slot = ks ? slotL1 : slotL0;
      bf16x8 bv[4], av[8];
      #pragma unroll
      for (int ni = 0; ni < 4; ++ni)
        bv[ni] = *(const bf16x8*)&Bt[(wn * 64 + ni * 16 + fr) * 64 + slot];
      #pragma unroll
      for (int mi = 0; mi < 8; ++mi)
        av[mi] = *(const bf16x8*)&At[(wm * 128 + mi * 16 + fr) * 64 + slot];
      __builtin_amdgcn_s_setprio(1);
      #pragma unroll
      for (int mi = 0; mi < 8; ++mi)
        #pragma unroll
        for (int ni = 0; ni < 4; ++ni)
          acc[mi][ni] = __builtin_amdgcn_mfma_f32_16x16x32_bf16(av[mi], bv[ni], acc[mi][ni], 0, 0, 0);
      __builtin_amdgcn_s_setprio(0);
    }
  }

  __syncthreads();
  #pragma unroll
  for (int mi = 0; mi < 8; ++mi) {
    const int row = wm * 128 + mi * 16 + fk * 4;
    #pragma unroll
    for (int ni = 0; ni < 4; ++ni) {
      const int colL = wn * 64 + ni * 16 + fr;
      const float qv = qws[((n0 + colL) / 48) % NB_];
      #pragma unroll
      for (int r = 0; r < 4; ++r)
        LDS_[(row + r) * 256 + colL] = (short)f2bf(fmaxf(acc[mi][ni][r], 0.f) * qv);
    }
  }
  __syncthreads();
  {
    const int row = t >> 1, h = t & 1;
    const unsigned short* src = (const unsigned short*)&LDS_[row * 256 + h * 128];
    unsigned short* dst = G + (size_t)(m0 + row) * ABC + n0 + h * 128;
    #pragma unroll
    for (int c = 0; c < 16; ++c)
      *(uint4*)(dst + c * 8) = *(const uint4*)(src + c * 8);
  }
}

// ---------------- GEMM2: P[sk][n][i] (bf16) = sum_{k in chunk} G[n][k]*DpT[i][k] ----------------
// Verified core: 256x192 tiles, grid 256 = one packed round.
__global__ __launch_bounds__(512, 1) void gemm2(const unsigned short* __restrict__ Gm,
                                                const unsigned short* __restrict__ DpT,
                                                unsigned short* __restrict__ P) {
  __shared__ short LDS_[57344];          // A[2][16384] + B[2][12288]
  short* Ab0 = LDS_;
  short* Bb0 = LDS_ + 32768;
  const int t = threadIdx.x;
  const int bid = blockIdx.x;            // 256 = 8 XCD * 32
  const int logical = (bid & 7) * 32 + (bid >> 3);
  const int sk = logical >> 3;
  const int rem = logical & 7;
  const int mt = rem >> 2, nt2 = rem & 3;
  const int m0 = mt * 256, n0 = nt2 * 192;
  const size_t kbase = (size_t)sk * KC;

  const int row0 = t >> 3;
  const int scol = ((t & 7) ^ (row0 & 7)) * 8;
  const unsigned short* Asrc = Gm  + (size_t)(m0 + row0) * ABC + kbase + scol;
  const unsigned short* Bsrc = DpT + (size_t)(n0 + row0) * ABC + kbase + scol;

  const int lane = t & 63, wid = t >> 6;
  const int wm = wid >> 2, wn = wid & 3;   // wave tile 128M x 48N
  const int fr = lane & 15, fk = lane >> 4;
  const int slotL0 = ((fk) ^ (fr & 7)) * 8;
  const int slotL1 = ((4 + fk) ^ (fr & 7)) * 8;

  f32x4 acc[8][3];
  #pragma unroll
  for (int i = 0; i < 8; ++i)
    #pragma unroll
    for (int j = 0; j < 3; ++j)
      #pragma unroll
      for (int k = 0; k < 4; ++k) acc[i][j][k] = 0.f;

  auto stage = [&](int b, int kt) {
    const unsigned short* ga = Asrc + kt * 64;
    const unsigned short* gb = Bsrc + kt * 64;
    short* la = Ab0 + b * 16384;
    short* lb = Bb0 + b * 12288;
    #pragma unroll
    for (int j = 0; j < 4; ++j)
      stage16(ga + (size_t)j * 64 * ABC, la + (j * 512 + t) * 8);
    #pragma unroll
    for (int j = 0; j < 3; ++j)
      stage16(gb + (size_t)j * 64 * ABC, lb + (j * 512 + t) * 8);
  };

  stage(0, 0);
  const int KT = KC / 64;   // 27
  for (int kt = 0; kt < KT; ++kt) {
    asm volatile("s_waitcnt vmcnt(0)" ::: "memory");
    __builtin_amdgcn_s_barrier();
    if (kt + 1 < KT) stage((kt + 1) & 1, kt + 1);
    const short* At = Ab0 + (kt & 1) * 16384;
    const short* Bt = Bb0 + (kt & 1) * 12288;
    #pragma unroll
    for (int ks = 0; ks < 2; ++ks) {
      const int slot = ks ? slotL1 : slotL0;
      bf16x8 bv[3], av[8];
      #pragma unroll
      for (int ni = 0; ni < 3; ++ni)
        bv[ni] = *(const bf16x8*)&Bt[(wn * 48 + ni * 16 + fr) * 64 + slot];
      #pragma unroll
      for (int mi = 0; mi < 8; ++mi)
        av[mi] = *(const bf16x8*)&At[(wm * 128 + mi * 16 + fr) * 64 + slot];
      __builtin_amdgcn_s_setprio(1);
      #pragma unroll
      for (int mi = 0; mi < 8; ++mi)
        #pragma unroll
        for (int ni = 0; ni < 3; ++ni)
          acc[mi][ni] = __builtin_amdgcn_mfma_f32_16x16x32_bf16(av[mi], bv[ni], acc[mi][ni], 0, 0, 0);
      __builtin_amdgcn_s_setprio(0);
    }
  }

  __syncthreads();
  #pragma unroll
  for (int mi = 0; mi < 8; ++mi) {
    const int row = wm * 128 + mi * 16 + fk * 4;
    #pragma unroll
    for (int ni = 0; ni < 3; ++ni) {
      const int colL = wn * 48 + ni * 16 + fr;
      #pragma unroll
      for (int r = 0; r < 4; ++r)
        LDS_[(row + r) * 192 + colL] = (short)f2bf(acc[mi][ni][r]);
    }
  }
  __syncthreads();
  {
    const int row = t >> 1, h = t & 1;
    const unsigned short* src = (const unsigned short*)&LDS_[row * 192 + h * 96];
    unsigned short* dst = P + (size_t)sk * BATCH * DIP +
                          (size_t)(m0 + row) * DIP + n0 + h * 96;
    #pragma unroll
    for (int c = 0; c < 12; ++c)
      *(uint4*)(dst + c * 8) = *(const uint4*)(src + c * 8);
  }
}

// ---------------- reduce: out[n][i] = sum_s P[s][n][i]  (bf16 partials) ----------------
__global__ __launch_bounds__(256) void reduce_p(const unsigned short* __restrict__ P,
                                                float* __restrict__ out) {
  const int u = blockIdx.x * 256 + threadIdx.x;
  const int n = u / (SDIM / 4), q = u % (SDIM / 4);
  const int i = q * 4;
  const unsigned short* base = P + (size_t)n * DIP + i;
  const size_t stride = (size_t)BATCH * DIP;
  float s0 = 0.f, s1 = 0.f, s2 = 0.f, s3 = 0.f;
  #pragma unroll 4
  for (int s = 0; s < SPLITK; ++s) {
    const uint2 v = *(const uint2*)(base + (size_t)s * stride);
    s0 += bf2f(v.x & 0xffffu);
    s1 += __uint_as_float(v.x & 0xffff0000u);
    s2 += bf2f(v.y & 0xffffu);
    s3 += __uint_as_float(v.y & 0xffff0000u);
  }
  float4 r; r.x = s0; r.y = s1; r.z = s2; r.w = s3;
  *(float4*)(out + (size_t)n * SDIM + i) = r;
}

// ---------------- fallback (no workspace): slow but correct ----------------
__global__ __launch_bounds__(256) void so3_fallback(const float* __restrict__ F,
                                                    const float* __restrict__ D,
                                                    const float* __restrict__ qw,
                                                    float* __restrict__ out) {
  const int n = blockIdx.x;
  __shared__ float fsh[SDIM];
  __shared__ float acc[SDIM];
  __shared__ float gch[256];
  for (int i = threadIdx.x; i < SDIM; i += 256) {
    fsh[i] = F[(size_t)n * SDIM + i];
    acc[i] = 0.f;
  }
  __syncthreads();
  for (int c0 = 0; c0 < ABC; c0 += 256) {
    const int r = c0 + threadIdx.x;
    const float* dr = D + (size_t)r * SDIM;
    float s = 0.f;
    for (int i = 0; i < SDIM; ++i) s += fsh[i] * dr[i];
    s = fmaxf(s, 0.f) * SQRT2F * qw[(r / 48) % NB_];
    gch[threadIdx.x] = s;
    __syncthreads();
    for (int i = threadIdx.x; i < SDIM; i += 256) {
      float a = 0.f;
      for (int tt = 0; tt < 256; ++tt) a += gch[tt] * D[(size_t)(c0 + tt) * SDIM + i];
      acc[i] += a;
    }
    __syncthreads();
  }
  for (int i = threadIdx.x; i < SDIM; i += 256) out[(size_t)n * SDIM + i] = acc[i];
}

// ---------------- launch ----------------
extern "C" void kernel_launch(void* const* d_in, const int* in_sizes, int n_in,
                              void* d_out, int out_size, void* d_ws, size_t ws_size,
                              hipStream_t stream) {
  const float* F  = (const float*)d_in[0];
  const float* D  = (const float*)d_in[1];
  const float* qw = (const float*)d_in[2];
  float* out = (float*)d_out;

  if (ws_size < WS_NEEDED) {
    so3_fallback<<<BATCH, 256, 0, stream>>>(F, D, qw, out);
    return;
  }

  unsigned short* Dp  = (unsigned short*)((char*)d_ws + DP_OFF);
  unsigned short* DpT = (unsigned short*)((char*)d_ws + DPT_OFF);
  unsigned short* Fp  = (unsigned short*)((char*)d_ws + FP_OFF);
  unsigned short* G   = (unsigned short*)((char*)d_ws + G_OFF);
  unsigned short* P   = (unsigned short*)((char*)d_ws + P_OFF);   // overlays Dp (dead after gemm1)

  conv_both<<<2592, 256, 0, stream>>>(D, Dp, DpT);
  convert_f<<<192, 256, 0, stream>>>(F, Fp);
  gemm1<<<432, 512, 0, stream>>>(Fp, Dp, qw, G);
  gemm2<<<256, 512, 0, stream>>>(G, DpT, P);
  reduce_p<<<340, 256, 0, stream>>>(P, out);
}